// Round 19
// baseline (3878.466 us; speedup 1.0000x reference)
//
#include <hip/hip_runtime.h>
#include <hip/hip_bf16.h>

typedef __bf16 bf16_t;

// MODEL (r19): d_out = FLOAT32, 68M f32.
//   Output0 @ [0:4M)   = out [B,S,D] (causal softmax(QK^T*8)@V@Wp^T+b) - PASSES (r16)
//   Output1 @ [4M:68M) = PER-HEAD SOFTMAX WEIGHTS [B,H,q,k], f32, masked->0.
//   (r16/r17/r18 all erred at exactly 416.0 = max|q(8s)| vs weights<=1 --
//    invariant to mask/transpose of my score-writing acts, as observed.)
// Pipeline: f64-exact naive self-MHA from x.

// ---- K1: qkv projection. grid (256, 3), block 256. 16 m-rows per block. ----
__global__ __launch_bounds__(256) void qkv_naive(
    const float* __restrict__ x, const float* __restrict__ W,
    float* __restrict__ Qf, float* __restrict__ Kf, bf16_t* __restrict__ Vbf)
{
    __shared__ float xs[16][1024];
    const int tid = threadIdx.x;
    const int m0 = blockIdx.x * 16;
    const int seg = blockIdx.y;          // 0=Q, 1=K, 2=V
    for (int i = tid; i < 16 * 1024; i += 256) {
        const int r = i >> 10, d = i & 1023;
        xs[r][d] = x[(size_t)(m0 + r) * 1024 + d];
    }
    __syncthreads();
    for (int u = 0; u < 4; ++u) {
        const int el = tid + u * 256;
        const int e  = seg * 1024 + el;
        const float* wrow = W + (size_t)e * 1024;
        double acc[16];
#pragma unroll
        for (int r = 0; r < 16; ++r) acc[r] = 0.0;
        for (int d = 0; d < 1024; ++d) {
            const double wv = (double)wrow[d];
#pragma unroll
            for (int r = 0; r < 16; ++r) acc[r] += (double)xs[r][d] * wv;
        }
        const int h = el >> 6, dh = el & 63;
#pragma unroll
        for (int r = 0; r < 16; ++r) {
            const int m = m0 + r, b = m >> 10, s = m & 1023;
            const size_t off = (((size_t)(b * 16 + h)) * 1024 + s) * 64 + dh;  // [B,H,S,DH]
            if (seg == 0)      Qf[off]  = (float)acc[r];
            else if (seg == 1) Kf[off]  = (float)acc[r];
            else               Vbf[off] = (bf16_t)(float)acc[r];
        }
    }
}

// ---- K2: causal softmax -> Output1 = WEIGHTS (f32) ; ctx. ----
__global__ __launch_bounds__(256) void attn_naive(
    const float* __restrict__ Qf, const float* __restrict__ Kf, const bf16_t* __restrict__ Vbf,
    float* __restrict__ attnW, bf16_t* __restrict__ ctxbf)
{
    __shared__ double sc[1024];
    __shared__ double red[256];
    __shared__ float qrow[64];
    const int q = blockIdx.x, bh = blockIdx.y;
    const int tid = threadIdx.x;
    if (tid < 64) qrow[tid] = Qf[((size_t)bh * 1024 + q) * 64 + tid];
    __syncthreads();

    // scores (x8) for k <= q, f64
    double lmx = -1e300;
    for (int k = tid; k <= q; k += 256) {
        const float* krow = Kf + ((size_t)bh * 1024 + k) * 64;
        double s = 0.0;
        for (int d = 0; d < 64; ++d) s += (double)qrow[d] * (double)krow[d];
        s *= 8.0;
        sc[k] = s;
        lmx = fmax(lmx, s);
    }
    red[tid] = lmx; __syncthreads();
    for (int off = 128; off > 0; off >>= 1) {
        if (tid < off) red[tid] = fmax(red[tid], red[tid + off]);
        __syncthreads();
    }
    const double mx = red[0];
    __syncthreads();

    double lz = 0.0;
    for (int k = tid; k <= q; k += 256) {
        const double e = exp(sc[k] - mx);
        sc[k] = e;
        lz += e;
    }
    red[tid] = lz; __syncthreads();
    for (int off = 128; off > 0; off >>= 1) {
        if (tid < off) red[tid] += red[tid + off];
        __syncthreads();
    }
    const double invZ = 1.0 / red[0];
    __syncthreads();

    // Output1: per-head softmax weights, f32, masked -> 0. Layout [bh][q][k].
    float* arow = attnW + ((size_t)bh * 1024 + q) * 1024;
    for (int k = tid; k < 1024; k += 256)
        arow[k] = (k <= q) ? (float)(sc[k] * invZ) : 0.0f;

    // ctx row: threads 0..63 each own one dh
    if (tid < 64) {
        const int dh = tid;
        double a = 0.0;
        for (int k = 0; k <= q; ++k)
            a += sc[k] * (double)(float)Vbf[((size_t)bh * 1024 + k) * 64 + dh];
        const int b = bh >> 4, h = bh & 15;
        ctxbf[((size_t)b * 1024 + q) * 1024 + h * 64 + dh] = (bf16_t)(float)(a * invZ);
    }
}

// ---- K3: out = ctx @ Wproj^T + bias (f32 out). grid 256, block 256. ----
__global__ __launch_bounds__(256) void proj_naive(
    const bf16_t* __restrict__ ctxbf, const float* __restrict__ Wp, const float* __restrict__ bias,
    float* __restrict__ out)
{
    __shared__ float cs[16][1024];
    const int tid = threadIdx.x;
    const int m0 = blockIdx.x * 16;
    for (int i = tid; i < 16 * 1024; i += 256) {
        const int r = i >> 10, d = i & 1023;
        cs[r][d] = (float)ctxbf[(size_t)(m0 + r) * 1024 + d];
    }
    __syncthreads();
    for (int u = 0; u < 4; ++u) {
        const int e = tid + u * 256;
        const float* wrow = Wp + (size_t)e * 1024;
        double acc[16];
#pragma unroll
        for (int r = 0; r < 16; ++r) acc[r] = 0.0;
        for (int d = 0; d < 1024; ++d) {
            const double wv = (double)wrow[d];
#pragma unroll
            for (int r = 0; r < 16; ++r) acc[r] += (double)cs[r][d] * wv;
        }
        const double bv = (double)bias[e];
#pragma unroll
        for (int r = 0; r < 16; ++r)
            out[(size_t)(m0 + r) * 1024 + e] = (float)(acc[r] + bv);
    }
}

extern "C" void kernel_launch(void* const* d_in, const int* in_sizes, int n_in,
                              void* d_out, int out_size, void* d_ws, size_t ws_size,
                              hipStream_t stream)
{
    // Inputs (all f32): x = first 4M tensor; weights by unique size.
    const float* big[3] = {nullptr, nullptr, nullptr}; int nbig = 0;
    const float* Wqkv = nullptr; const float* Wproj = nullptr; const float* bproj = nullptr;
    for (int i = 0; i < n_in; ++i) {
        const int sz = in_sizes[i];
        if (sz == 4194304)      { if (nbig < 3) big[nbig++] = (const float*)d_in[i]; }
        else if (sz == 3145728) { Wqkv  = (const float*)d_in[i]; }
        else if (sz == 1048576) { Wproj = (const float*)d_in[i]; }
        else if (sz == 1024)    { bproj = (const float*)d_in[i]; }
    }
    const float* x = big[0];

    float* out   = (float*)d_out;                        // f32 [B,S,D]
    float* attnW = out + (size_t)4194304;                // f32 [B,H,S,S] weights

    char* wsb = (char*)d_ws;                             // 48 MB used
    float*  Qf    = (float*)wsb;                         // 16 MB  [B,H,S,DH] f32
    float*  Kf    = (float*)(wsb + ((size_t)16 << 20));  // 16 MB  [B,H,S,DH] f32
    bf16_t* Vbf   = (bf16_t*)(wsb + ((size_t)32 << 20)); //  8 MB  [B,H,S,DH] bf16
    bf16_t* ctxbf = (bf16_t*)(wsb + ((size_t)40 << 20)); //  8 MB  [B,S,D]    bf16

    qkv_naive<<<dim3(256, 3), 256, 0, stream>>>(x, Wqkv, Qf, Kf, Vbf);
    attn_naive<<<dim3(1024, 64), 256, 0, stream>>>(Qf, Kf, Vbf, attnW, ctxbf);
    proj_naive<<<256, 256, 0, stream>>>(ctxbf, Wproj, bproj, out);
}

// Round 20
// 271.061 us; speedup vs baseline: 14.3085x; 14.3085x over previous
//
#include <hip/hip_runtime.h>
#include <hip/hip_bf16.h>

typedef __bf16 bf16_t;
typedef __bf16 bf16x8 __attribute__((ext_vector_type(8)));
typedef __bf16 bf16x4 __attribute__((ext_vector_type(4)));
typedef float f32x4 __attribute__((ext_vector_type(4)));
typedef unsigned int u32;

#define MFMA16 __builtin_amdgcn_mfma_f32_16x16x32_bf16
static constexpr float MASKV = -1.0e30f;
static constexpr int Sdim = 1024;

__device__ __forceinline__ void gload16(const void* g, void* l) {
    __builtin_amdgcn_global_load_lds((const __attribute__((address_space(1))) u32*)g,
                                     (__attribute__((address_space(3))) u32*)l, 16, 0, 0);
}

__device__ __forceinline__ void splt2(float v, bf16_t* h, bf16_t* l) {
    const bf16_t hv = (bf16_t)v;
    *h = hv; *l = (bf16_t)(v - (float)hv);
}

// ---- split f32 inputs into bf16 hi/lo planes (x, W_qkv) + bf16 W_proj ----
static constexpr int QX = 1048576;   // x quads
static constexpr int QW = 786432;    // W_qkv quads

__global__ __launch_bounds__(256) void split2_k(
    const float* __restrict__ x, const float* __restrict__ wqkv, const float* __restrict__ wproj,
    bf16_t* __restrict__ xh, bf16_t* __restrict__ xl,
    bf16_t* __restrict__ wh, bf16_t* __restrict__ wl, bf16_t* __restrict__ wp)
{
    int q = blockIdx.x * 256 + threadIdx.x;
    const int stride = 2048 * 256;
#pragma unroll
    for (int it = 0; it < 4; ++it, q += stride) {
        if (q < QX + QW) {
            const float* src; bf16_t *dh, *dl;
            if (q < QX) { src = x + (size_t)q * 4; dh = xh + (size_t)q * 4; dl = xl + (size_t)q * 4; }
            else { const int r = q - QX; src = wqkv + (size_t)r * 4; dh = wh + (size_t)r * 4; dl = wl + (size_t)r * 4; }
            const f32x4 v = *(const f32x4*)src;
            bf16x4 hv, lv;
#pragma unroll
            for (int c = 0; c < 4; ++c) { bf16_t a, b; splt2(v[c], &a, &b); hv[c] = a; lv[c] = b; }
            *(bf16x4*)dh = hv; *(bf16x4*)dl = lv;
        } else {
            const int r = q - QX - QW;
            const f32x4 v = *(const f32x4*)(wproj + (size_t)r * 4);
            bf16x4 hv;
#pragma unroll
            for (int c = 0; c < 4; ++c) hv[c] = (bf16_t)v[c];
            *(bf16x4*)(wp + (size_t)r * 4) = hv;
        }
    }
}

// ---- QKV GEMM: 128x128 tile, hi/lo 3-product for Q/K, 1-product for V ----
// C[m,e] = sum_k x[m,k]*Wqkv[e,k]. Q,K -> f32 [B,H,S,DH]; V -> bf16 [B,H,DH,S].
__global__ __launch_bounds__(256) void gemm_qkv(
    const bf16_t* __restrict__ Ah_g, const bf16_t* __restrict__ Al_g,
    const bf16_t* __restrict__ Bh_g, const bf16_t* __restrict__ Bl_g,
    float* __restrict__ Qf, float* __restrict__ Kf, bf16_t* __restrict__ Vt)
{
    __shared__ bf16_t Ah[128 * 32], Al[128 * 32], Bh[128 * 32], Bl[128 * 32];
    const int tid = threadIdx.x, w = tid >> 6, lane = tid & 63;
    const int lm = lane & 15, hi = lane >> 4;
    const int wr = w >> 1, wc = w & 1;
    const int m0 = blockIdx.x * 128, n0 = blockIdx.y * 128;
    const int isel = n0 >> 10;           // 0=Q,1=K,2=V (block-uniform)
    const bool three = (isel < 2);

    f32x4 acc[4][4] = {};

    for (int kt = 0; kt < 32; ++kt) {
        __syncthreads();
#pragma unroll
        for (int c = 0; c < 2; ++c) {
            const int j = c * 256 + tid;
            const int r = j >> 2, cg = (j & 3) << 3;
            const int base = (c * 256 + w * 64) * 8;   // wave-uniform LDS dest
            const size_t goa = (size_t)(m0 + r) * 1024 + kt * 32 + cg;
            const size_t gob = (size_t)(n0 + r) * 1024 + kt * 32 + cg;
            gload16(Ah_g + goa, &Ah[base]);
            gload16(Bh_g + gob, &Bh[base]);
            if (three) {
                gload16(Al_g + goa, &Al[base]);
                gload16(Bl_g + gob, &Bl[base]);
            }
        }
        __syncthreads();

        bf16x8 ah[4], bh[4], al[4], bl[4];
#pragma unroll
        for (int mi = 0; mi < 4; ++mi)
            ah[mi] = *(const bf16x8*)&Ah[(wr * 64 + mi * 16 + lm) * 32 + hi * 8];
#pragma unroll
        for (int ni = 0; ni < 4; ++ni)
            bh[ni] = *(const bf16x8*)&Bh[(wc * 64 + ni * 16 + lm) * 32 + hi * 8];
        if (three) {
#pragma unroll
            for (int mi = 0; mi < 4; ++mi)
                al[mi] = *(const bf16x8*)&Al[(wr * 64 + mi * 16 + lm) * 32 + hi * 8];
#pragma unroll
            for (int ni = 0; ni < 4; ++ni)
                bl[ni] = *(const bf16x8*)&Bl[(wc * 64 + ni * 16 + lm) * 32 + hi * 8];
        }
#pragma unroll
        for (int mi = 0; mi < 4; ++mi)
#pragma unroll
            for (int ni = 0; ni < 4; ++ni) {
                if (three) {
                    acc[mi][ni] = MFMA16(ah[mi], bl[ni], acc[mi][ni], 0, 0, 0);
                    acc[mi][ni] = MFMA16(al[mi], bh[ni], acc[mi][ni], 0, 0, 0);
                }
                acc[mi][ni] = MFMA16(ah[mi], bh[ni], acc[mi][ni], 0, 0, 0);
            }
    }

#pragma unroll
    for (int mi = 0; mi < 4; ++mi)
#pragma unroll
        for (int ni = 0; ni < 4; ++ni)
#pragma unroll
            for (int j = 0; j < 4; ++j) {
                const float v = acc[mi][ni][j];
                const int m = m0 + wr * 64 + mi * 16 + hi * 4 + j;   // token
                const int e = n0 + wc * 64 + ni * 16 + lm;           // feature [0,3072)
                const int b = m >> 10, s = m & 1023;
                const int h = (e >> 6) & 15, dh = e & 63;
                if (isel == 0)
                    Qf[(((size_t)(b * 16 + h)) * Sdim + s) * 64 + dh] = v;
                else if (isel == 1)
                    Kf[(((size_t)(b * 16 + h)) * Sdim + s) * 64 + dh] = v;
                else
                    Vt[(((size_t)(b * 16 + h)) * 64 + dh) * Sdim + s] = (bf16_t)v;
            }
}

// ---- fused attention: hi/lo scores, f32 softmax, f32 weight rows, PV ----
__global__ __launch_bounds__(256) void attn_k(
    const float* __restrict__ Qf, const float* __restrict__ Kf,
    const bf16_t* __restrict__ Vt, float* __restrict__ attnW, bf16_t* __restrict__ ctx)
{
    constexpr int PITCH = 1036;
    __shared__ float S[16][PITCH];
    const int qt = blockIdx.x, bh = blockIdx.y;
    const int q0 = qt * 16;
    const int tid = threadIdx.x, w = tid >> 6, lane = tid & 63;
    const int lm = lane & 15, hi = lane >> 4;
    const int KT = qt + 1, KT16 = KT * 16;

    // --- Phase A: scores (x8), causal-masked -> S ---
    const float* qp = Qf + ((size_t)bh * Sdim + q0 + lm) * 64 + hi * 8;
    bf16x8 qh0, ql0, qh1, ql1;
    {
        const f32x4 a0 = *(const f32x4*)qp,        a1 = *(const f32x4*)(qp + 4);
        const f32x4 b0 = *(const f32x4*)(qp + 32), b1 = *(const f32x4*)(qp + 36);
#pragma unroll
        for (int i = 0; i < 4; ++i) {
            bf16_t h, l;
            splt2(a0[i], &h, &l); qh0[i] = h;   ql0[i] = l;
            splt2(a1[i], &h, &l); qh0[i+4] = h; ql0[i+4] = l;
            splt2(b0[i], &h, &l); qh1[i] = h;   ql1[i] = l;
            splt2(b1[i], &h, &l); qh1[i+4] = h; ql1[i+4] = l;
        }
    }

    for (int kt = w; kt < KT; kt += 4) {
        const float* kp = Kf + ((size_t)bh * Sdim + kt * 16 + lm) * 64 + hi * 8;
        bf16x8 kh0, kl0, kh1, kl1;
        {
            const f32x4 a0 = *(const f32x4*)kp,        a1 = *(const f32x4*)(kp + 4);
            const f32x4 b0 = *(const f32x4*)(kp + 32), b1 = *(const f32x4*)(kp + 36);
#pragma unroll
            for (int i = 0; i < 4; ++i) {
                bf16_t h, l;
                splt2(a0[i], &h, &l); kh0[i] = h;   kl0[i] = l;
                splt2(a1[i], &h, &l); kh0[i+4] = h; kl0[i+4] = l;
                splt2(b0[i], &h, &l); kh1[i] = h;   kl1[i] = l;
                splt2(b1[i], &h, &l); kh1[i+4] = h; kl1[i+4] = l;
            }
        }
        f32x4 t = {0.f, 0.f, 0.f, 0.f};
        t = MFMA16(ql0, kh0, t, 0, 0, 0);
        t = MFMA16(ql1, kh1, t, 0, 0, 0);
        t = MFMA16(qh0, kl0, t, 0, 0, 0);
        t = MFMA16(qh1, kl1, t, 0, 0, 0);
        t = MFMA16(qh0, kh0, t, 0, 0, 0);
        t = MFMA16(qh1, kh1, t, 0, 0, 0);
        const int c = kt * 16 + lm;
#pragma unroll
        for (int j = 0; j < 4; ++j) {
            const int r = hi * 4 + j;
            S[r][c] = (c <= q0 + r) ? t[j] * 8.0f : MASKV;
        }
    }
    __syncthreads();

    // --- Phase B: softmax per row; write f32 weight rows (masked -> 0) ---
#pragma unroll
    for (int rr = 0; rr < 4; ++rr) {
        const int r = w * 4 + rr;
        float mx = MASKV;
        for (int cb = 0; cb < Sdim; cb += 256) {
            if (cb >= KT16) break;
            const int c = cb + lane * 4;
            const f32x4 v = *(const f32x4*)&S[r][c];
#pragma unroll
            for (int cc = 0; cc < 4; ++cc)
                if (c + cc < KT16) mx = fmaxf(mx, v[cc]);
        }
#pragma unroll
        for (int dd = 1; dd < 64; dd <<= 1) mx = fmaxf(mx, __shfl_xor(mx, dd));

        float z = 0.f;
        for (int cb = 0; cb < Sdim; cb += 256) {
            const int c = cb + lane * 4;
            const f32x4 v = *(const f32x4*)&S[r][c];
            f32x4 e;
#pragma unroll
            for (int cc = 0; cc < 4; ++cc) {
                const float a = fmaxf(v[cc] - mx, -87.0f);
                const float ev = (c + cc < KT16) ? __expf(a) : 0.f;
                e[cc] = ev; z += ev;
            }
            *(f32x4*)&S[r][c] = e;
        }
#pragma unroll
        for (int dd = 1; dd < 64; dd <<= 1) z += __shfl_xor(z, dd);
        const float invZ = 1.0f / z;

        float* arow = attnW + ((size_t)bh * Sdim + q0 + r) * Sdim;
        for (int cb = 0; cb < Sdim; cb += 256) {
            const int c = cb + lane * 4;
            const f32x4 e = *(const f32x4*)&S[r][c];
            f32x4 p;
#pragma unroll
            for (int cc = 0; cc < 4; ++cc) p[cc] = e[cc] * invZ;
            *(f32x4*)&S[r][c] = p;
            *(f32x4*)(arow + c) = p;
        }
    }
    __syncthreads();

    // --- Phase C: ctx = P @ V ---
    f32x4 acc = {0.f, 0.f, 0.f, 0.f};
    const int steps = (KT16 + 31) >> 5;
    const bf16_t* vtp = Vt + ((size_t)bh * 64 + w * 16 + lm) * Sdim;
    for (int ks = 0; ks < steps; ++ks) {
        const int kb = ks * 32 + hi * 8;
        const f32x4 v0 = *(const f32x4*)&S[lm][kb];
        const f32x4 v1 = *(const f32x4*)&S[lm][kb + 4];
        bf16x8 a;
#pragma unroll
        for (int i = 0; i < 4; ++i) { a[i] = (bf16_t)v0[i]; a[i + 4] = (bf16_t)v1[i]; }
        const bf16x8 bfr = *(const bf16x8*)(vtp + kb);
        acc = MFMA16(a, bfr, acc, 0, 0, 0);
    }
    const int bb = bh >> 4, h = bh & 15;
#pragma unroll
    for (int j = 0; j < 4; ++j) {
        const int s = q0 + hi * 4 + j;
        ctx[((size_t)bb * Sdim + s) * 1024 + h * 64 + w * 16 + lm] = (bf16_t)acc[j];
    }
}

// ---- output projection: bf16 MFMA, f32 out + bias ----
__global__ __launch_bounds__(256) void gemm_proj(
    const bf16_t* __restrict__ A, const bf16_t* __restrict__ Bw,
    const float* __restrict__ bias, float* __restrict__ out)
{
    __shared__ bf16_t As[128 * 32];
    __shared__ bf16_t Bs[128 * 32];
    const int tid = threadIdx.x, w = tid >> 6, lane = tid & 63;
    const int lm = lane & 15, hi = lane >> 4;
    const int wr = w >> 1, wc = w & 1;
    const int m0 = blockIdx.x * 128, n0 = blockIdx.y * 128;

    f32x4 acc[4][4] = {};
    for (int kt = 0; kt < 32; ++kt) {
        __syncthreads();
#pragma unroll
        for (int c = 0; c < 2; ++c) {
            const int j = c * 256 + tid;
            const int r = j >> 2, cg = (j & 3) << 3;
            const int base = (c * 256 + w * 64) * 8;
            gload16(A  + (size_t)(m0 + r) * 1024 + kt * 32 + cg, &As[base]);
            gload16(Bw + (size_t)(n0 + r) * 1024 + kt * 32 + cg, &Bs[base]);
        }
        __syncthreads();
        bf16x8 af[4], bfr[4];
#pragma unroll
        for (int mi = 0; mi < 4; ++mi)
            af[mi] = *(const bf16x8*)&As[(wr * 64 + mi * 16 + lm) * 32 + hi * 8];
#pragma unroll
        for (int ni = 0; ni < 4; ++ni)
            bfr[ni] = *(const bf16x8*)&Bs[(wc * 64 + ni * 16 + lm) * 32 + hi * 8];
#pragma unroll
        for (int mi = 0; mi < 4; ++mi)
#pragma unroll
            for (int ni = 0; ni < 4; ++ni)
                acc[mi][ni] = MFMA16(af[mi], bfr[ni], acc[mi][ni], 0, 0, 0);
    }
#pragma unroll
    for (int mi = 0; mi < 4; ++mi)
#pragma unroll
        for (int ni = 0; ni < 4; ++ni) {
            const int e = n0 + wc * 64 + ni * 16 + lm;
            const float bv = bias[e];
#pragma unroll
            for (int j = 0; j < 4; ++j) {
                const int m = m0 + wr * 64 + mi * 16 + hi * 4 + j;
                out[(size_t)m * 1024 + e] = acc[mi][ni][j] + bv;
            }
        }
}

extern "C" void kernel_launch(void* const* d_in, const int* in_sizes, int n_in,
                              void* d_out, int out_size, void* d_ws, size_t ws_size,
                              hipStream_t stream)
{
    const float* big[3] = {nullptr, nullptr, nullptr}; int nbig = 0;
    const float* Wqkv = nullptr; const float* Wproj = nullptr; const float* bproj = nullptr;
    for (int i = 0; i < n_in; ++i) {
        const int sz = in_sizes[i];
        if (sz == 4194304)      { if (nbig < 3) big[nbig++] = (const float*)d_in[i]; }
        else if (sz == 3145728) { Wqkv  = (const float*)d_in[i]; }
        else if (sz == 1048576) { Wproj = (const float*)d_in[i]; }
        else if (sz == 1024)    { bproj = (const float*)d_in[i]; }
    }
    const float* x = big[0];

    float* out   = (float*)d_out;                        // f32 [B,S,D]
    float* attnW = out + (size_t)4194304;                // f32 [B,H,S,S] weights

    // Park split planes in the attn region (consumed by gemm_qkv, overwritten later)
    bf16_t* xh = (bf16_t*)attnW;                         // 8 MB
    bf16_t* xl = xh + (size_t)4194304;                   // 8 MB
    bf16_t* wh = xl + (size_t)4194304;                   // 6 MB
    bf16_t* wl = wh + (size_t)3145728;                   // 6 MB (28 MB < 256 MB)

    char* wsb = (char*)d_ws;                             // 50 MB used
    float*  Qf  = (float*)wsb;                           // 16 MB [B,H,S,DH] f32
    float*  Kf  = (float*)(wsb + ((size_t)16 << 20));    // 16 MB
    bf16_t* Vt  = (bf16_t*)(wsb + ((size_t)32 << 20));   //  8 MB [B,H,DH,S] bf16
    bf16_t* ctx = (bf16_t*)(wsb + ((size_t)40 << 20));   //  8 MB [B,S,D] bf16
    bf16_t* wp  = (bf16_t*)(wsb + ((size_t)48 << 20));   //  2 MB

    split2_k<<<2048, 256, 0, stream>>>(x, Wqkv, Wproj, xh, xl, wh, wl, wp);
    gemm_qkv<<<dim3(32, 24), 256, 0, stream>>>(xh, xl, wh, wl, Qf, Kf, Vt);
    attn_k<<<dim3(64, 64), 256, 0, stream>>>(Qf, Kf, Vt, attnW, ctx);
    gemm_proj<<<dim3(32, 8), 256, 0, stream>>>(ctx, wp, bproj, out);
}

// Round 21
// 253.245 us; speedup vs baseline: 15.3151x; 1.0704x over previous
//
#include <hip/hip_runtime.h>
#include <hip/hip_bf16.h>

typedef __bf16 bf16_t;
typedef __bf16 bf16x8 __attribute__((ext_vector_type(8)));
typedef __bf16 bf16x4 __attribute__((ext_vector_type(4)));
typedef float f32x4 __attribute__((ext_vector_type(4)));
typedef unsigned int u32;

#define MFMA16 __builtin_amdgcn_mfma_f32_16x16x32_bf16
static constexpr float MASKV = -1.0e30f;
static constexpr int Sdim = 1024;

__device__ __forceinline__ void gload16(const void* g, void* l) {
    __builtin_amdgcn_global_load_lds((const __attribute__((address_space(1))) u32*)g,
                                     (__attribute__((address_space(3))) u32*)l, 16, 0, 0);
}

__device__ __forceinline__ void splt2(float v, bf16_t* h, bf16_t* l) {
    const bf16_t hv = (bf16_t)v;
    *h = hv; *l = (bf16_t)(v - (float)hv);
}

// ---- split f32 inputs into bf16 hi/lo planes (x, W_qkv) + bf16 W_proj ----
static constexpr int QX = 1048576;
static constexpr int QW = 786432;

__global__ __launch_bounds__(256) void split2_k(
    const float* __restrict__ x, const float* __restrict__ wqkv, const float* __restrict__ wproj,
    bf16_t* __restrict__ xh, bf16_t* __restrict__ xl,
    bf16_t* __restrict__ wh, bf16_t* __restrict__ wl, bf16_t* __restrict__ wp)
{
    int q = blockIdx.x * 256 + threadIdx.x;
    const int stride = 2048 * 256;
#pragma unroll
    for (int it = 0; it < 4; ++it, q += stride) {
        if (q < QX + QW) {
            const float* src; bf16_t *dh, *dl;
            if (q < QX) { src = x + (size_t)q * 4; dh = xh + (size_t)q * 4; dl = xl + (size_t)q * 4; }
            else { const int r = q - QX; src = wqkv + (size_t)r * 4; dh = wh + (size_t)r * 4; dl = wl + (size_t)r * 4; }
            const f32x4 v = *(const f32x4*)src;
            bf16x4 hv, lv;
#pragma unroll
            for (int c = 0; c < 4; ++c) { bf16_t a, b; splt2(v[c], &a, &b); hv[c] = a; lv[c] = b; }
            *(bf16x4*)dh = hv; *(bf16x4*)dl = lv;
        } else {
            const int r = q - QX - QW;
            const f32x4 v = *(const f32x4*)(wproj + (size_t)r * 4);
            bf16x4 hv;
#pragma unroll
            for (int c = 0; c < 4; ++c) hv[c] = (bf16_t)v[c];
            *(bf16x4*)(wp + (size_t)r * 4) = hv;
        }
    }
}

// ---- QKV GEMM: hi/lo 3-product for Q/K -> PRE-SPLIT bf16 planes; V -> bf16 T ----
__global__ __launch_bounds__(256) void gemm_qkv(
    const bf16_t* __restrict__ Ah_g, const bf16_t* __restrict__ Al_g,
    const bf16_t* __restrict__ Bh_g, const bf16_t* __restrict__ Bl_g,
    bf16_t* __restrict__ Qhi, bf16_t* __restrict__ Qlo,
    bf16_t* __restrict__ Khi, bf16_t* __restrict__ Klo, bf16_t* __restrict__ Vt)
{
    __shared__ bf16_t Ah[128 * 32], Al[128 * 32], Bh[128 * 32], Bl[128 * 32];
    const int tid = threadIdx.x, w = tid >> 6, lane = tid & 63;
    const int lm = lane & 15, hi = lane >> 4;
    const int wr = w >> 1, wc = w & 1;
    const int m0 = blockIdx.x * 128, n0 = blockIdx.y * 128;
    const int isel = n0 >> 10;
    const bool three = (isel < 2);

    f32x4 acc[4][4] = {};

    for (int kt = 0; kt < 32; ++kt) {
        __syncthreads();
#pragma unroll
        for (int c = 0; c < 2; ++c) {
            const int j = c * 256 + tid;
            const int r = j >> 2, cg = (j & 3) << 3;
            const int base = (c * 256 + w * 64) * 8;
            const size_t goa = (size_t)(m0 + r) * 1024 + kt * 32 + cg;
            const size_t gob = (size_t)(n0 + r) * 1024 + kt * 32 + cg;
            gload16(Ah_g + goa, &Ah[base]);
            gload16(Bh_g + gob, &Bh[base]);
            if (three) {
                gload16(Al_g + goa, &Al[base]);
                gload16(Bl_g + gob, &Bl[base]);
            }
        }
        __syncthreads();

        bf16x8 ah[4], bh[4], al[4], bl[4];
#pragma unroll
        for (int mi = 0; mi < 4; ++mi)
            ah[mi] = *(const bf16x8*)&Ah[(wr * 64 + mi * 16 + lm) * 32 + hi * 8];
#pragma unroll
        for (int ni = 0; ni < 4; ++ni)
            bh[ni] = *(const bf16x8*)&Bh[(wc * 64 + ni * 16 + lm) * 32 + hi * 8];
        if (three) {
#pragma unroll
            for (int mi = 0; mi < 4; ++mi)
                al[mi] = *(const bf16x8*)&Al[(wr * 64 + mi * 16 + lm) * 32 + hi * 8];
#pragma unroll
            for (int ni = 0; ni < 4; ++ni)
                bl[ni] = *(const bf16x8*)&Bl[(wc * 64 + ni * 16 + lm) * 32 + hi * 8];
        }
#pragma unroll
        for (int mi = 0; mi < 4; ++mi)
#pragma unroll
            for (int ni = 0; ni < 4; ++ni) {
                if (three) {
                    acc[mi][ni] = MFMA16(ah[mi], bl[ni], acc[mi][ni], 0, 0, 0);
                    acc[mi][ni] = MFMA16(al[mi], bh[ni], acc[mi][ni], 0, 0, 0);
                }
                acc[mi][ni] = MFMA16(ah[mi], bh[ni], acc[mi][ni], 0, 0, 0);
            }
    }

#pragma unroll
    for (int mi = 0; mi < 4; ++mi)
#pragma unroll
        for (int ni = 0; ni < 4; ++ni)
#pragma unroll
            for (int j = 0; j < 4; ++j) {
                const float v = acc[mi][ni][j];
                const int m = m0 + wr * 64 + mi * 16 + hi * 4 + j;
                const int e = n0 + wc * 64 + ni * 16 + lm;
                const int b = m >> 10, s = m & 1023;
                const int h = (e >> 6) & 15, dh = e & 63;
                if (isel < 2) {
                    const size_t off = (((size_t)(b * 16 + h)) * Sdim + s) * 64 + dh;
                    bf16_t hv, lv; splt2(v, &hv, &lv);
                    if (isel == 0) { Qhi[off] = hv; Qlo[off] = lv; }
                    else           { Khi[off] = hv; Klo[off] = lv; }
                } else {
                    Vt[(((size_t)(b * 16 + h)) * 64 + dh) * Sdim + s] = (bf16_t)v;
                }
            }
}

// ---- fused attention: pre-split frags, 2-tile ILP scores, f32 softmax+weights, PV ----
__global__ __launch_bounds__(256) void attn_k(
    const bf16_t* __restrict__ Qhi, const bf16_t* __restrict__ Qlo,
    const bf16_t* __restrict__ Khi, const bf16_t* __restrict__ Klo,
    const bf16_t* __restrict__ Vt, float* __restrict__ attnW, bf16_t* __restrict__ ctx)
{
    constexpr int PITCH = 1036;
    __shared__ float S[16][PITCH];
    const int bh = blockIdx.x;              // bh-major: pins bh to one XCD (64%8==0)
    const int qt = 63 - blockIdx.y;         // heaviest q-tiles dispatched first
    const int q0 = qt * 16;
    const int tid = threadIdx.x, w = tid >> 6, lane = tid & 63;
    const int lm = lane & 15, hi = lane >> 4;
    const int KT = qt + 1, KT16 = KT * 16;

    // --- Phase A: scores (x8), causal-masked -> S; 2 k-tiles in flight ---
    const size_t qoff = ((size_t)bh * Sdim + q0 + lm) * 64 + hi * 8;
    const bf16x8 qh0 = *(const bf16x8*)(Qhi + qoff);
    const bf16x8 qh1 = *(const bf16x8*)(Qhi + qoff + 32);
    const bf16x8 ql0 = *(const bf16x8*)(Qlo + qoff);
    const bf16x8 ql1 = *(const bf16x8*)(Qlo + qoff + 32);

    const bf16_t* Khb = Khi + (size_t)bh * Sdim * 64;
    const bf16_t* Klb = Klo + (size_t)bh * Sdim * 64;

    for (int kt = w; kt < KT; kt += 8) {
        const size_t o1 = (size_t)(kt * 16 + lm) * 64 + hi * 8;
        const bf16x8 kh0a = *(const bf16x8*)(Khb + o1);
        const bf16x8 kh1a = *(const bf16x8*)(Khb + o1 + 32);
        const bf16x8 kl0a = *(const bf16x8*)(Klb + o1);
        const bf16x8 kl1a = *(const bf16x8*)(Klb + o1 + 32);
        const int kt2 = kt + 4;
        const bool has2 = (kt2 < KT);
        bf16x8 kh0b = kh0a, kh1b = kh1a, kl0b = kl0a, kl1b = kl1a;
        if (has2) {
            const size_t o2 = (size_t)(kt2 * 16 + lm) * 64 + hi * 8;
            kh0b = *(const bf16x8*)(Khb + o2);
            kh1b = *(const bf16x8*)(Khb + o2 + 32);
            kl0b = *(const bf16x8*)(Klb + o2);
            kl1b = *(const bf16x8*)(Klb + o2 + 32);
        }
        f32x4 t0 = {0.f, 0.f, 0.f, 0.f}, t1 = {0.f, 0.f, 0.f, 0.f};
        t0 = MFMA16(ql0, kh0a, t0, 0, 0, 0);
        t1 = MFMA16(ql0, kh0b, t1, 0, 0, 0);
        t0 = MFMA16(ql1, kh1a, t0, 0, 0, 0);
        t1 = MFMA16(ql1, kh1b, t1, 0, 0, 0);
        t0 = MFMA16(qh0, kl0a, t0, 0, 0, 0);
        t1 = MFMA16(qh0, kl0b, t1, 0, 0, 0);
        t0 = MFMA16(qh1, kl1a, t0, 0, 0, 0);
        t1 = MFMA16(qh1, kl1b, t1, 0, 0, 0);
        t0 = MFMA16(qh0, kh0a, t0, 0, 0, 0);
        t1 = MFMA16(qh0, kh0b, t1, 0, 0, 0);
        t0 = MFMA16(qh1, kh1a, t0, 0, 0, 0);
        t1 = MFMA16(qh1, kh1b, t1, 0, 0, 0);
        const int c1 = kt * 16 + lm;
#pragma unroll
        for (int j = 0; j < 4; ++j) {
            const int r = hi * 4 + j;
            S[r][c1] = (c1 <= q0 + r) ? t0[j] * 8.0f : MASKV;
        }
        if (has2) {
            const int c2 = kt2 * 16 + lm;
#pragma unroll
            for (int j = 0; j < 4; ++j) {
                const int r = hi * 4 + j;
                S[r][c2] = (c2 <= q0 + r) ? t1[j] * 8.0f : MASKV;
            }
        }
    }
    __syncthreads();

    // --- Phase B: softmax per row; write f32 weight rows (masked -> 0) ---
#pragma unroll
    for (int rr = 0; rr < 4; ++rr) {
        const int r = w * 4 + rr;
        float mx = MASKV;
        for (int cb = 0; cb < Sdim; cb += 256) {
            if (cb >= KT16) break;
            const int c = cb + lane * 4;
            const f32x4 v = *(const f32x4*)&S[r][c];
#pragma unroll
            for (int cc = 0; cc < 4; ++cc)
                if (c + cc < KT16) mx = fmaxf(mx, v[cc]);
        }
#pragma unroll
        for (int dd = 1; dd < 64; dd <<= 1) mx = fmaxf(mx, __shfl_xor(mx, dd));

        float z = 0.f;
        for (int cb = 0; cb < Sdim; cb += 256) {
            const int c = cb + lane * 4;
            const f32x4 v = *(const f32x4*)&S[r][c];
            f32x4 e;
#pragma unroll
            for (int cc = 0; cc < 4; ++cc) {
                const float a = fmaxf(v[cc] - mx, -87.0f);
                const float ev = (c + cc < KT16) ? __expf(a) : 0.f;
                e[cc] = ev; z += ev;
            }
            *(f32x4*)&S[r][c] = e;
        }
#pragma unroll
        for (int dd = 1; dd < 64; dd <<= 1) z += __shfl_xor(z, dd);
        const float invZ = 1.0f / z;

        float* arow = attnW + ((size_t)bh * Sdim + q0 + r) * Sdim;
        for (int cb = 0; cb < Sdim; cb += 256) {
            const int c = cb + lane * 4;
            const f32x4 e = *(const f32x4*)&S[r][c];
            f32x4 p;
#pragma unroll
            for (int cc = 0; cc < 4; ++cc) p[cc] = e[cc] * invZ;
            *(f32x4*)&S[r][c] = p;
            *(f32x4*)(arow + c) = p;
        }
    }
    __syncthreads();

    // --- Phase C: ctx = P @ V (2 independent accumulators for ILP) ---
    f32x4 acc0 = {0.f, 0.f, 0.f, 0.f}, acc1 = {0.f, 0.f, 0.f, 0.f};
    const int steps = (KT16 + 31) >> 5;
    const bf16_t* vtp = Vt + ((size_t)bh * 64 + w * 16 + lm) * Sdim;
    for (int ks = 0; ks < steps; ks += 2) {
        {
            const int kb = ks * 32 + hi * 8;
            const f32x4 v0 = *(const f32x4*)&S[lm][kb];
            const f32x4 v1 = *(const f32x4*)&S[lm][kb + 4];
            bf16x8 a;
#pragma unroll
            for (int i = 0; i < 4; ++i) { a[i] = (bf16_t)v0[i]; a[i + 4] = (bf16_t)v1[i]; }
            acc0 = MFMA16(a, *(const bf16x8*)(vtp + kb), acc0, 0, 0, 0);
        }
        if (ks + 1 < steps) {
            const int kb = (ks + 1) * 32 + hi * 8;
            const f32x4 v0 = *(const f32x4*)&S[lm][kb];
            const f32x4 v1 = *(const f32x4*)&S[lm][kb + 4];
            bf16x8 a;
#pragma unroll
            for (int i = 0; i < 4; ++i) { a[i] = (bf16_t)v0[i]; a[i + 4] = (bf16_t)v1[i]; }
            acc1 = MFMA16(a, *(const bf16x8*)(vtp + kb), acc1, 0, 0, 0);
        }
    }
    const f32x4 acc = acc0 + acc1;
    const int bb = bh >> 4, h = bh & 15;
#pragma unroll
    for (int j = 0; j < 4; ++j) {
        const int s = q0 + hi * 4 + j;
        ctx[((size_t)bb * Sdim + s) * 1024 + h * 64 + w * 16 + lm] = (bf16_t)acc[j];
    }
}

// ---- output projection: bf16 MFMA, f32 out + bias ----
__global__ __launch_bounds__(256) void gemm_proj(
    const bf16_t* __restrict__ A, const bf16_t* __restrict__ Bw,
    const float* __restrict__ bias, float* __restrict__ out)
{
    __shared__ bf16_t As[128 * 32];
    __shared__ bf16_t Bs[128 * 32];
    const int tid = threadIdx.x, w = tid >> 6, lane = tid & 63;
    const int lm = lane & 15, hi = lane >> 4;
    const int wr = w >> 1, wc = w & 1;
    const int m0 = blockIdx.x * 128, n0 = blockIdx.y * 128;

    f32x4 acc[4][4] = {};
    for (int kt = 0; kt < 32; ++kt) {
        __syncthreads();
#pragma unroll
        for (int c = 0; c < 2; ++c) {
            const int j = c * 256 + tid;
            const int r = j >> 2, cg = (j & 3) << 3;
            const int base = (c * 256 + w * 64) * 8;
            gload16(A  + (size_t)(m0 + r) * 1024 + kt * 32 + cg, &As[base]);
            gload16(Bw + (size_t)(n0 + r) * 1024 + kt * 32 + cg, &Bs[base]);
        }
        __syncthreads();
        bf16x8 af[4], bfr[4];
#pragma unroll
        for (int mi = 0; mi < 4; ++mi)
            af[mi] = *(const bf16x8*)&As[(wr * 64 + mi * 16 + lm) * 32 + hi * 8];
#pragma unroll
        for (int ni = 0; ni < 4; ++ni)
            bfr[ni] = *(const bf16x8*)&Bs[(wc * 64 + ni * 16 + lm) * 32 + hi * 8];
#pragma unroll
        for (int mi = 0; mi < 4; ++mi)
#pragma unroll
            for (int ni = 0; ni < 4; ++ni)
                acc[mi][ni] = MFMA16(af[mi], bfr[ni], acc[mi][ni], 0, 0, 0);
    }
#pragma unroll
    for (int mi = 0; mi < 4; ++mi)
#pragma unroll
        for (int ni = 0; ni < 4; ++ni) {
            const int e = n0 + wc * 64 + ni * 16 + lm;
            const float bv = bias[e];
#pragma unroll
            for (int j = 0; j < 4; ++j) {
                const int m = m0 + wr * 64 + mi * 16 + hi * 4 + j;
                out[(size_t)m * 1024 + e] = acc[mi][ni][j] + bv;
            }
        }
}

extern "C" void kernel_launch(void* const* d_in, const int* in_sizes, int n_in,
                              void* d_out, int out_size, void* d_ws, size_t ws_size,
                              hipStream_t stream)
{
    const float* big[3] = {nullptr, nullptr, nullptr}; int nbig = 0;
    const float* Wqkv = nullptr; const float* Wproj = nullptr; const float* bproj = nullptr;
    for (int i = 0; i < n_in; ++i) {
        const int sz = in_sizes[i];
        if (sz == 4194304)      { if (nbig < 3) big[nbig++] = (const float*)d_in[i]; }
        else if (sz == 3145728) { Wqkv  = (const float*)d_in[i]; }
        else if (sz == 1048576) { Wproj = (const float*)d_in[i]; }
        else if (sz == 1024)    { bproj = (const float*)d_in[i]; }
    }
    const float* x = big[0];

    float* out   = (float*)d_out;                        // f32 [B,S,D]
    float* attnW = out + (size_t)4194304;                // f32 [B,H,S,S] weights

    // Park input split planes in the attn region (consumed before attn_k writes)
    bf16_t* xh = (bf16_t*)attnW;
    bf16_t* xl = xh + (size_t)4194304;
    bf16_t* wh = xl + (size_t)4194304;
    bf16_t* wl = wh + (size_t)3145728;                   // 28 MB < 256 MB

    char* wsb = (char*)d_ws;                             // 50 MB used
    bf16_t* Qhi = (bf16_t*)wsb;                          // 8 MB [B,H,S,DH]
    bf16_t* Qlo = (bf16_t*)(wsb + ((size_t)8  << 20));   // 8 MB
    bf16_t* Khi = (bf16_t*)(wsb + ((size_t)16 << 20));   // 8 MB
    bf16_t* Klo = (bf16_t*)(wsb + ((size_t)24 << 20));   // 8 MB
    bf16_t* Vt  = (bf16_t*)(wsb + ((size_t)32 << 20));   // 8 MB [B,H,DH,S]
    bf16_t* ctx = (bf16_t*)(wsb + ((size_t)40 << 20));   // 8 MB [B,S,D]
    bf16_t* wp  = (bf16_t*)(wsb + ((size_t)48 << 20));   // 2 MB

    split2_k<<<2048, 256, 0, stream>>>(x, Wqkv, Wproj, xh, xl, wh, wl, wp);
    gemm_qkv<<<dim3(32, 24), 256, 0, stream>>>(xh, xl, wh, wl, Qhi, Qlo, Khi, Klo, Vt);
    attn_k<<<dim3(64, 64), 256, 0, stream>>>(Qhi, Qlo, Khi, Klo, Vt, attnW, ctx);
    gemm_proj<<<dim3(32, 8), 256, 0, stream>>>(ctx, wp, bproj, out);
}